// Round 1
// baseline (860.209 us; speedup 1.0000x reference)
//
#include <hip/hip_runtime.h>
#include <math.h>

#define XG 432
#define YG 496
#define NPTS 32
#define COUT 64

__constant__ const float kVX = 0.16f;
__constant__ const float kVY = 0.16f;
__constant__ const float kXOFF = 0.08f;
__constant__ const float kYOFF = -39.60f;

// One wave (64 lanes) per pillar; lane index = output channel.
// Block = 256 threads = 4 waves = 4 pillars.
__global__ __launch_bounds__(256) void pillar_mlp_kernel(
    const float* __restrict__ pillars,   // (P, 32, 4)
    const int*   __restrict__ coors,     // (P, 4) : b, x, y, 0
    const int*   __restrict__ npp,       // (P,)
    const float* __restrict__ W1,        // (64, 6)
    const float* __restrict__ g1, const float* __restrict__ b1,
    const float* __restrict__ m1, const float* __restrict__ v1,
    const float* __restrict__ W2,        // (64, 64)
    const float* __restrict__ g2, const float* __restrict__ b2,
    const float* __restrict__ m2, const float* __restrict__ v2,
    float* __restrict__ pooled,          // (P, 64)
    int*   __restrict__ winner,          // (B, YG, XG), pre-set to -1
    int P)
{
    __shared__ float sfeat[4][NPTS][6];
    __shared__ float sh1[4][NPTS][COUT];

    const int w    = threadIdx.x >> 6;
    const int lane = threadIdx.x & 63;
    const int p    = blockIdx.x * 4 + w;
    const int pc   = (p < P) ? p : (P - 1);   // clamp so every thread reaches barriers

    // ---- load points (point n = 4 consecutive floats = one float4) ----
    float4 pt = make_float4(0.f, 0.f, 0.f, 0.f);
    if (lane < NPTS) pt = ((const float4*)pillars)[(size_t)pc * NPTS + lane];

    // sum of xyz over ALL 32 points (reference sums all N, divides by npoints)
    float sx = pt.x, sy = pt.y, sz = pt.z;
    #pragma unroll
    for (int m = 32; m >= 1; m >>= 1) {
        sx += __shfl_xor(sx, m);
        sy += __shfl_xor(sy, m);
        sz += __shfl_xor(sz, m);
    }
    const int   np     = npp[pc];
    const float inv_np = 1.0f / (float)np;
    const float cx = sx * inv_np, cy = sy * inv_np, cz = sz * inv_np;

    const int cb  = coors[pc * 4 + 0];
    const int cxg = coors[pc * 4 + 1];
    const int cyg = coors[pc * 4 + 2];
    const float px = (float)cxg * kVX + kXOFF;
    const float py = (float)cyg * kVY + kYOFF;

    if (lane < NPTS) {
        const bool valid = lane < np;
        sfeat[w][lane][0] = valid ? pt.z        : 0.f;
        sfeat[w][lane][1] = valid ? pt.x - cx   : 0.f;
        sfeat[w][lane][2] = valid ? pt.y - cy   : 0.f;
        sfeat[w][lane][3] = valid ? pt.z - cz   : 0.f;
        sfeat[w][lane][4] = valid ? pt.x - px   : 0.f;
        sfeat[w][lane][5] = valid ? pt.y - py   : 0.f;
    }

    // ---- per-lane (= per-channel) weights and BN params ----
    const int c = lane;
    float w1c[6];
    #pragma unroll
    for (int k = 0; k < 6; ++k) w1c[k] = W1[c * 6 + k];
    const float s1  = g1[c] * rsqrtf(v1[c] + 1e-5f);
    const float bb1 = b1[c], mm1 = m1[c];
    const float s2  = g2[c] * rsqrtf(v2[c] + 1e-5f);
    const float bb2 = b2[c], mm2 = m2[c];

    float w2c[COUT];
    const float4* W2v = (const float4*)(W2 + c * COUT);
    #pragma unroll
    for (int k = 0; k < COUT / 4; ++k) {
        float4 t = W2v[k];
        w2c[4 * k + 0] = t.x; w2c[4 * k + 1] = t.y;
        w2c[4 * k + 2] = t.z; w2c[4 * k + 3] = t.w;
    }

    __syncthreads();

    // ---- MLP1 + BN1 + ReLU -> LDS ----
    #pragma unroll 4
    for (int n = 0; n < NPTS; ++n) {
        float pre = 0.f;
        #pragma unroll
        for (int k = 0; k < 6; ++k) pre += sfeat[w][n][k] * w1c[k];
        float h = (pre - mm1) * s1 + bb1;
        sh1[w][n][c] = fmaxf(h, 0.f);
    }

    __syncthreads();

    // ---- MLP2 + BN2 + max-pool over points ----
    float mx = -INFINITY;
    for (int n = 0; n < NPTS; ++n) {
        float pre = 0.f;
        const float4* hv = (const float4*)&sh1[w][n][0];
        #pragma unroll
        for (int k = 0; k < COUT / 4; ++k) {
            float4 t = hv[k];  // wave-uniform broadcast read
            pre += t.x * w2c[4 * k + 0];
            pre += t.y * w2c[4 * k + 1];
            pre += t.z * w2c[4 * k + 2];
            pre += t.w * w2c[4 * k + 3];
        }
        float h = (pre - mm2) * s2 + bb2;
        mx = fmaxf(mx, h);
    }

    if (p < P) {
        pooled[(size_t)p * COUT + c] = mx;
        if (lane == 0) {
            // numpy advanced-index assignment: last write wins -> highest p wins
            atomicMax(&winner[cb * (YG * XG) + cyg * XG + cxg], p);
        }
    }
}

// One thread per 4 consecutive output elements (along X). Fully coalesced
// write of the entire (B, 64, YG, XG) output; zeros where no pillar landed.
__global__ __launch_bounds__(256) void scatter_kernel(
    const float* __restrict__ pooled,
    const int*   __restrict__ winner,
    float4* __restrict__ out, int total4)
{
    int i = blockIdx.x * blockDim.x + threadIdx.x;
    if (i >= total4) return;
    int idx = i * 4;
    int x = idx % XG;
    int t = idx / XG;
    int y = t % YG;
    t = t / YG;
    int ch = t & (COUT - 1);
    int b  = t >> 6;

    const int4 wn = *(const int4*)(winner + b * (YG * XG) + y * XG + x);
    float4 o;
    o.x = (wn.x >= 0) ? pooled[(size_t)wn.x * COUT + ch] : 0.f;
    o.y = (wn.y >= 0) ? pooled[(size_t)wn.y * COUT + ch] : 0.f;
    o.z = (wn.z >= 0) ? pooled[(size_t)wn.z * COUT + ch] : 0.f;
    o.w = (wn.w >= 0) ? pooled[(size_t)wn.w * COUT + ch] : 0.f;
    out[i] = o;
}

extern "C" void kernel_launch(void* const* d_in, const int* in_sizes, int n_in,
                              void* d_out, int out_size, void* d_ws, size_t ws_size,
                              hipStream_t stream) {
    const float* pillars = (const float*)d_in[0];
    const int*   coors   = (const int*)d_in[1];
    const int*   npp     = (const int*)d_in[2];
    // d_in[3] = batch_size (derive from out_size instead; no device read needed)
    const float* W1 = (const float*)d_in[4];
    const float* g1 = (const float*)d_in[5];
    const float* b1 = (const float*)d_in[6];
    const float* m1 = (const float*)d_in[7];
    const float* v1 = (const float*)d_in[8];
    const float* W2 = (const float*)d_in[9];
    const float* g2 = (const float*)d_in[10];
    const float* b2 = (const float*)d_in[11];
    const float* m2 = (const float*)d_in[12];
    const float* v2 = (const float*)d_in[13];

    const int P = in_sizes[2];                       // 64000
    const int B = out_size / (COUT * YG * XG);       // 4

    float* pooled = (float*)d_ws;
    int*   winner = (int*)((char*)d_ws + (size_t)P * COUT * sizeof(float));

    // winner = -1 everywhere (0xFF bytes)
    hipMemsetAsync(winner, 0xFF, (size_t)B * YG * XG * sizeof(int), stream);

    const int nblk = (P + 3) / 4;
    pillar_mlp_kernel<<<nblk, 256, 0, stream>>>(
        pillars, coors, npp, W1, g1, b1, m1, v1, W2, g2, b2, m2, v2,
        pooled, winner, P);

    const int total4 = out_size / 4;
    scatter_kernel<<<(total4 + 255) / 256, 256, 0, stream>>>(
        pooled, winner, (float4*)d_out, total4);
}

// Round 2
// 419.050 us; speedup vs baseline: 2.0528x; 2.0528x over previous
//
#include <hip/hip_runtime.h>
#include <math.h>

#define XG 432
#define YG 496
#define NPTS 32
#define COUT 64
#define ROWB 72   // padded h1 row length in bf16 elements (144 B, 16B-aligned)

typedef __attribute__((ext_vector_type(8))) __bf16 bf16x8;
typedef __attribute__((ext_vector_type(16))) float f32x16;

union ABFrag { bf16x8 v; short s[8]; };

__device__ __forceinline__ short f2bf(float f) {
    unsigned u = __builtin_bit_cast(unsigned, f);
    u = (u + 0x7fffu + ((u >> 16) & 1u)) >> 16;
    return (short)u;
}

// One wave per pillar, block = 4 waves = 4 pillars.
// MLP1 and MLP2 both via v_mfma_f32_32x32x16_bf16.
__global__ __launch_bounds__(256) void pillar_mlp_kernel(
    const float* __restrict__ pillars,   // (P, 32, 4)
    const int*   __restrict__ coors,     // (P, 4) : b, x, y, 0
    const int*   __restrict__ npp,       // (P,)
    const float* __restrict__ W1,        // (64, 6)
    const float* __restrict__ g1, const float* __restrict__ b1,
    const float* __restrict__ m1, const float* __restrict__ v1,
    const float* __restrict__ W2,        // (64, 64)
    const float* __restrict__ g2, const float* __restrict__ b2,
    const float* __restrict__ m2, const float* __restrict__ v2,
    float* __restrict__ pooledT,         // (64, P)  transposed!
    int*   __restrict__ winner,          // (B, YG, XG), pre-set to -1
    int P)
{
    __shared__ short sh1[4][NPTS * ROWB];  // 4 * 4608 B = 18432 B
    __shared__ float sout[4][COUT];        // 1024 B

    const int w      = threadIdx.x >> 6;
    const int lane   = threadIdx.x & 63;
    const int half   = lane >> 5;          // 0: k 0..7, 1: k 8..15 of each K-tile
    const int lane31 = lane & 31;
    const int p      = blockIdx.x * 4 + w;
    const int pc     = (p < P) ? p : (P - 1);

    // ---- load point (lane = point index for lanes 0..31) ----
    float4 pt = make_float4(0.f, 0.f, 0.f, 0.f);
    if (lane < NPTS) pt = ((const float4*)pillars)[(size_t)pc * NPTS + lane];

    // sum xyz over the 32 points (lanes 0..31 only; masks <=16 stay in-half)
    float sx = pt.x, sy = pt.y, sz = pt.z;
    #pragma unroll
    for (int m = 1; m <= 16; m <<= 1) {
        sx += __shfl_xor(sx, m);
        sy += __shfl_xor(sy, m);
        sz += __shfl_xor(sz, m);
    }
    const int   np     = npp[pc];
    const float inv_np = 1.0f / (float)np;
    const float cx = sx * inv_np, cy = sy * inv_np, cz = sz * inv_np;

    const int cb  = coors[pc * 4 + 0];
    const int cxg = coors[pc * 4 + 1];
    const int cyg = coors[pc * 4 + 2];
    const float px = (float)cxg * 0.16f + 0.08f;
    const float py = (float)cyg * 0.16f + (-39.60f);

    // ---- B-fragments for MLP2: B[k=c_in][n=c_out], n=lane31, k=half*8+j ----
    ABFrag b2f[2][4];
    #pragma unroll
    for (int t = 0; t < 2; ++t) {
        const int co = t * 32 + lane31;
        #pragma unroll
        for (int kt = 0; kt < 4; ++kt) {
            const int ci = kt * 16 + half * 8;
            const float4 wa = *(const float4*)(W2 + co * COUT + ci);
            const float4 wb = *(const float4*)(W2 + co * COUT + ci + 4);
            b2f[t][kt].s[0] = f2bf(wa.x); b2f[t][kt].s[1] = f2bf(wa.y);
            b2f[t][kt].s[2] = f2bf(wa.z); b2f[t][kt].s[3] = f2bf(wa.w);
            b2f[t][kt].s[4] = f2bf(wb.x); b2f[t][kt].s[5] = f2bf(wb.y);
            b2f[t][kt].s[6] = f2bf(wb.z); b2f[t][kt].s[7] = f2bf(wb.w);
        }
    }

    // ---- A-fragment for MLP1: A[m=point][k], m=lane31, k=half*8+j (K=16 pad) ----
    ABFrag a1;
    #pragma unroll
    for (int j = 0; j < 8; ++j) a1.s[j] = 0;
    if (lane < NPTS && lane < np) {
        a1.s[0] = f2bf(pt.z);
        a1.s[1] = f2bf(pt.x - cx);
        a1.s[2] = f2bf(pt.y - cy);
        a1.s[3] = f2bf(pt.z - cz);
        a1.s[4] = f2bf(pt.x - px);
        a1.s[5] = f2bf(pt.y - py);
    }

    // ---- B-fragments for MLP1: W1^T padded to K=16 ----
    ABFrag b1f[2];
    #pragma unroll
    for (int t = 0; t < 2; ++t) {
        #pragma unroll
        for (int j = 0; j < 8; ++j) b1f[t].s[j] = 0;
        if (half == 0) {
            const int co = t * 32 + lane31;
            #pragma unroll
            for (int k = 0; k < 6; ++k) b1f[t].s[k] = f2bf(W1[co * 6 + k]);
        }
    }

    // ---- MLP1 MFMA: pre1 (32 points x 64 channels) ----
    f32x16 d10, d11;
    #pragma unroll
    for (int i = 0; i < 16; ++i) { d10[i] = 0.f; d11[i] = 0.f; }
    d10 = __builtin_amdgcn_mfma_f32_32x32x16_bf16(a1.v, b1f[0].v, d10, 0, 0, 0);
    d11 = __builtin_amdgcn_mfma_f32_32x32x16_bf16(a1.v, b1f[1].v, d11, 0, 0, 0);

    // ---- BN1 + ReLU -> LDS h1[point][channel] (bf16, padded rows) ----
    float s1a[2], bb1a[2], s2a[2], bb2a[2];
    #pragma unroll
    for (int t = 0; t < 2; ++t) {
        const int co = t * 32 + lane31;
        const float s1 = g1[co] * rsqrtf(v1[co] + 1e-5f);
        s1a[t]  = s1;
        bb1a[t] = b1[co] - m1[co] * s1;
        const float s2 = g2[co] * rsqrtf(v2[co] + 1e-5f);
        s2a[t]  = s2;
        bb2a[t] = b2[co] - m2[co] * s2;
    }
    #pragma unroll
    for (int r = 0; r < 16; ++r) {
        const int point = (r & 3) + 8 * (r >> 2) + 4 * half;
        const float h0 = fmaxf(d10[r] * s1a[0] + bb1a[0], 0.f);
        const float h1 = fmaxf(d11[r] * s1a[1] + bb1a[1], 0.f);
        sh1[w][point * ROWB + lane31]      = f2bf(h0);
        sh1[w][point * ROWB + 32 + lane31] = f2bf(h1);
    }

    __syncthreads();

    // ---- MLP2: A from LDS (4 ds_read_b128), 8 MFMA ----
    bf16x8 a2[4];
    #pragma unroll
    for (int kt = 0; kt < 4; ++kt) {
        a2[kt] = *(const bf16x8*)&sh1[w][lane31 * ROWB + kt * 16 + half * 8];
    }
    f32x16 c0, c1;
    #pragma unroll
    for (int i = 0; i < 16; ++i) { c0[i] = 0.f; c1[i] = 0.f; }
    #pragma unroll
    for (int kt = 0; kt < 4; ++kt) {
        c0 = __builtin_amdgcn_mfma_f32_32x32x16_bf16(a2[kt], b2f[0][kt].v, c0, 0, 0, 0);
        c1 = __builtin_amdgcn_mfma_f32_32x32x16_bf16(a2[kt], b2f[1][kt].v, c1, 0, 0, 0);
    }

    // ---- BN2 + max-pool over points ----
    float mx0 = -INFINITY, mx1 = -INFINITY;
    #pragma unroll
    for (int r = 0; r < 16; ++r) {
        mx0 = fmaxf(mx0, c0[r] * s2a[0] + bb2a[0]);
        mx1 = fmaxf(mx1, c1[r] * s2a[1] + bb2a[1]);
    }
    mx0 = fmaxf(mx0, __shfl_xor(mx0, 32));
    mx1 = fmaxf(mx1, __shfl_xor(mx1, 32));
    // lane < 32 holds channel lane (tile0); lane >= 32 holds channel lane (tile1)
    sout[w][lane] = half ? mx1 : mx0;

    if (p < P && lane == 0) {
        atomicMax(&winner[cb * (YG * XG) + cyg * XG + cxg], p);
    }

    __syncthreads();

    // ---- transposed pooled write: pooledT[c][p], 16B per 4 threads ----
    const int c  = threadIdx.x >> 2;
    const int pi = threadIdx.x & 3;
    const int pp = blockIdx.x * 4 + pi;
    if (pp < P) pooledT[(size_t)c * P + pp] = sout[pi][c];
}

// One thread per 4 consecutive output elements (along X). Fully coalesced
// write of the entire (B, 64, YG, XG) output; gathers from pooledT so the
// per-channel slice (256 KB) stays L2-resident.
__global__ __launch_bounds__(256) void scatter_kernel(
    const float* __restrict__ pooledT,
    const int*   __restrict__ winner,
    float4* __restrict__ out, int total4, int P)
{
    int i = blockIdx.x * blockDim.x + threadIdx.x;
    if (i >= total4) return;
    int idx = i * 4;
    int x = idx % XG;
    int t = idx / XG;
    int y = t % YG;
    t = t / YG;
    int ch = t & (COUT - 1);
    int b  = t >> 6;

    const int4 wn = *(const int4*)(winner + b * (YG * XG) + y * XG + x);
    const float* pl = pooledT + (size_t)ch * P;
    float4 o;
    o.x = (wn.x >= 0) ? pl[wn.x] : 0.f;
    o.y = (wn.y >= 0) ? pl[wn.y] : 0.f;
    o.z = (wn.z >= 0) ? pl[wn.z] : 0.f;
    o.w = (wn.w >= 0) ? pl[wn.w] : 0.f;
    out[i] = o;
}

extern "C" void kernel_launch(void* const* d_in, const int* in_sizes, int n_in,
                              void* d_out, int out_size, void* d_ws, size_t ws_size,
                              hipStream_t stream) {
    const float* pillars = (const float*)d_in[0];
    const int*   coors   = (const int*)d_in[1];
    const int*   npp     = (const int*)d_in[2];
    const float* W1 = (const float*)d_in[4];
    const float* g1 = (const float*)d_in[5];
    const float* b1 = (const float*)d_in[6];
    const float* m1 = (const float*)d_in[7];
    const float* v1 = (const float*)d_in[8];
    const float* W2 = (const float*)d_in[9];
    const float* g2 = (const float*)d_in[10];
    const float* b2 = (const float*)d_in[11];
    const float* m2 = (const float*)d_in[12];
    const float* v2 = (const float*)d_in[13];

    const int P = in_sizes[2];                       // 64000
    const int B = out_size / (COUT * YG * XG);       // 4

    float* pooledT = (float*)d_ws;
    int*   winner  = (int*)((char*)d_ws + (size_t)COUT * P * sizeof(float));

    // winner = -1 everywhere (0xFF bytes)
    hipMemsetAsync(winner, 0xFF, (size_t)B * YG * XG * sizeof(int), stream);

    const int nblk = (P + 3) / 4;
    pillar_mlp_kernel<<<nblk, 256, 0, stream>>>(
        pillars, coors, npp, W1, g1, b1, m1, v1, W2, g2, b2, m2, v2,
        pooledT, winner, P);

    const int total4 = out_size / 4;
    scatter_kernel<<<(total4 + 255) / 256, 256, 0, stream>>>(
        pooledT, winner, (float4*)d_out, total4, P);
}

// Round 4
// 347.455 us; speedup vs baseline: 2.4757x; 1.2061x over previous
//
#include <hip/hip_runtime.h>
#include <math.h>

#define XG 432
#define YG 496
#define NPTS 32
#define COUT 64
#define ROWH 72      // halfwords per LDS h1 row (144 B)
#define TILE 64      // x-positions per scatter block

typedef __attribute__((ext_vector_type(8))) __bf16 bf16x8;
typedef __attribute__((ext_vector_type(16))) float f32x16;

union ABFrag { bf16x8 v; unsigned short s[8]; };

__device__ __forceinline__ unsigned short f2bf(float f) {
    unsigned u = __builtin_bit_cast(unsigned, f);
    u = (u + 0x7fffu + ((u >> 16) & 1u)) >> 16;
    return (unsigned short)u;
}

// ---------------------------------------------------------------------------
// One-block precompute: bf16 MFMA fragments for W1/W2 (+ channel permutation
// for the interleaved h1 layout) and folded BN scale/bias.
//   h1 LDS position k' holds channel sigma(k') = (k'&1)*32 + (k'>>1).
// ---------------------------------------------------------------------------
__global__ __launch_bounds__(256) void precompute_kernel(
    const float* __restrict__ W1,
    const float* __restrict__ g1, const float* __restrict__ b1,
    const float* __restrict__ m1, const float* __restrict__ v1,
    const float* __restrict__ W2,
    const float* __restrict__ g2, const float* __restrict__ b2,
    const float* __restrict__ m2, const float* __restrict__ v2,
    unsigned short* __restrict__ w1f,   // [2][64][8]
    unsigned short* __restrict__ w2f,   // [2][4][64][8]
    float* __restrict__ bnp)            // [4][64]
{
    const int t = threadIdx.x;
    // W1 fragments (B[k=feature][n=c_out], K padded 6->16)
    if (t < 128) {
        const int tt = t >> 6, lane = t & 63;
        const int half = lane >> 5, l31 = lane & 31;
        unsigned short vals[8] = {0,0,0,0,0,0,0,0};
        if (half == 0) {
            const int co = tt * 32 + l31;
            for (int k = 0; k < 6; ++k) vals[k] = f2bf(W1[co * 6 + k]);
        }
        for (int j = 0; j < 8; ++j) w1f[(tt * 64 + lane) * 8 + j] = vals[j];
    }
    // folded BN params
    if (t < 64) {
        const float s1 = g1[t] * rsqrtf(v1[t] + 1e-5f);
        bnp[t]       = s1;
        bnp[64 + t]  = b1[t] - m1[t] * s1;
        const float s2 = g2[t] * rsqrtf(v2[t] + 1e-5f);
        bnp[128 + t] = s2;
        bnp[192 + t] = b2[t] - m2[t] * s2;
    }
    // W2 fragments, channel-permuted K
    for (int idx = t; idx < 512; idx += 256) {
        const int tt   = idx >> 8;
        const int kt   = (idx >> 6) & 3;
        const int lane = idx & 63;
        const int half = lane >> 5, l31 = lane & 31;
        const int co = tt * 32 + l31;
        for (int j = 0; j < 8; ++j) {
            const int kp = kt * 16 + half * 8 + j;
            const int ci = ((kp & 1) << 5) | (kp >> 1);   // sigma(kp)
            w2f[((tt * 4 + kt) * 64 + lane) * 8 + j] = f2bf(W2[co * COUT + ci]);
        }
    }
}

// ---------------------------------------------------------------------------
// One wave per pillar, 4 waves/block. MLP1+MLP2 via v_mfma_f32_32x32x16_bf16.
// No __syncthreads: each wave owns its private LDS slab.
// ---------------------------------------------------------------------------
__global__ __launch_bounds__(256) void pillar_mlp_kernel(
    const float* __restrict__ pillars,   // (P, 32, 4)
    const int*   __restrict__ coors,     // (P, 4) : b, x, y, 0
    const int*   __restrict__ npp,       // (P,)
    const unsigned short* __restrict__ w1f,
    const unsigned short* __restrict__ w2f,
    const float* __restrict__ bnp,
    float* __restrict__ pooled,          // (P, 64)
    int*   __restrict__ winner,          // (B, YG, XG), pre-set to -1
    int P)
{
    __shared__ unsigned int sh1[4][NPTS * (ROWH / 2)];   // 18432 B

    const int w    = threadIdx.x >> 6;
    const int lane = threadIdx.x & 63;
    const int half = lane >> 5;
    const int l31  = lane & 31;
    const int p    = blockIdx.x * 4 + w;
    const int pc   = (p < P) ? p : (P - 1);

    // ---- pre-converted fragments (coalesced dwordx4, L2-hot) ----
    const bf16x8* w2v = (const bf16x8*)w2f;
    bf16x8 b2f[8];
    #pragma unroll
    for (int i = 0; i < 8; ++i) b2f[i] = w2v[i * 64 + lane];
    const bf16x8* w1v = (const bf16x8*)w1f;
    const bf16x8 b1f0 = w1v[lane];
    const bf16x8 b1f1 = w1v[64 + lane];

    float s1a[2], bb1a[2], s2a[2], bb2a[2];
    #pragma unroll
    for (int t = 0; t < 2; ++t) {
        const int co = t * 32 + l31;
        s1a[t]  = bnp[co];
        bb1a[t] = bnp[64 + co];
        s2a[t]  = bnp[128 + co];
        bb2a[t] = bnp[192 + co];
    }

    // ---- point load + center reduction ----
    float4 pt = make_float4(0.f, 0.f, 0.f, 0.f);
    if (lane < NPTS) pt = ((const float4*)pillars)[(size_t)pc * NPTS + lane];
    float sx = pt.x, sy = pt.y, sz = pt.z;
    #pragma unroll
    for (int m = 1; m <= 16; m <<= 1) {
        sx += __shfl_xor(sx, m);
        sy += __shfl_xor(sy, m);
        sz += __shfl_xor(sz, m);
    }
    const int   np     = npp[pc];
    const float inv_np = 1.0f / (float)np;
    const float cx = sx * inv_np, cy = sy * inv_np, cz = sz * inv_np;

    const int cb  = coors[pc * 4 + 0];
    const int cxg = coors[pc * 4 + 1];
    const int cyg = coors[pc * 4 + 2];
    const float px = (float)cxg * 0.16f + 0.08f;
    const float py = (float)cyg * 0.16f + (-39.60f);

    // ---- A-fragment for MLP1 (lane = point for lanes 0..31, K pad 16) ----
    ABFrag a1;
    #pragma unroll
    for (int j = 0; j < 8; ++j) a1.s[j] = 0;
    if (lane < np) {           // np <= 32, so lane < NPTS implied
        a1.s[0] = f2bf(pt.z);
        a1.s[1] = f2bf(pt.x - cx);
        a1.s[2] = f2bf(pt.y - cy);
        a1.s[3] = f2bf(pt.z - cz);
        a1.s[4] = f2bf(pt.x - px);
        a1.s[5] = f2bf(pt.y - py);
    }

    // ---- MLP1 ----
    f32x16 d0, d1;
    #pragma unroll
    for (int i = 0; i < 16; ++i) { d0[i] = 0.f; d1[i] = 0.f; }
    d0 = __builtin_amdgcn_mfma_f32_32x32x16_bf16(a1.v, b1f0, d0, 0, 0, 0);
    d1 = __builtin_amdgcn_mfma_f32_32x32x16_bf16(a1.v, b1f1, d1, 0, 0, 0);

    // ---- BN1 + ReLU -> LDS, interleaved channels, packed b32 writes ----
    unsigned int* row = sh1[w];
    #pragma unroll
    for (int r = 0; r < 16; ++r) {
        const int point = (r & 3) + 8 * (r >> 2) + 4 * half;
        const float h0 = fmaxf(d0[r] * s1a[0] + bb1a[0], 0.f);
        const float h1 = fmaxf(d1[r] * s1a[1] + bb1a[1], 0.f);
        const unsigned pk = (unsigned)f2bf(h0) | ((unsigned)f2bf(h1) << 16);
        row[point * (ROWH / 2) + l31] = pk;
    }

    // ---- MLP2: A from own slab (4 ds_read_b128), 8 MFMA ----
    const unsigned short* rowh = (const unsigned short*)sh1[w];
    bf16x8 a2[4];
    #pragma unroll
    for (int kt = 0; kt < 4; ++kt)
        a2[kt] = *(const bf16x8*)(rowh + l31 * ROWH + kt * 16 + half * 8);

    f32x16 c0, c1;
    #pragma unroll
    for (int i = 0; i < 16; ++i) { c0[i] = 0.f; c1[i] = 0.f; }
    #pragma unroll
    for (int kt = 0; kt < 4; ++kt) {
        c0 = __builtin_amdgcn_mfma_f32_32x32x16_bf16(a2[kt], b2f[kt],     c0, 0, 0, 0);
        c1 = __builtin_amdgcn_mfma_f32_32x32x16_bf16(a2[kt], b2f[4 + kt], c1, 0, 0, 0);
    }

    // ---- BN2 + max-pool ----
    float mx0 = -INFINITY, mx1 = -INFINITY;
    #pragma unroll
    for (int r = 0; r < 16; ++r) {
        mx0 = fmaxf(mx0, c0[r] * s2a[0] + bb2a[0]);
        mx1 = fmaxf(mx1, c1[r] * s2a[1] + bb2a[1]);
    }
    mx0 = fmaxf(mx0, __shfl_xor(mx0, 32));
    mx1 = fmaxf(mx1, __shfl_xor(mx1, 32));

    if (p < P) {
        pooled[(size_t)p * COUT + lane] = half ? mx1 : mx0;   // lane == channel
        if (lane == 0)
            atomicMax(&winner[cb * (YG * XG) + cyg * XG + cxg], p);
    }
}

// ---------------------------------------------------------------------------
// Tile scatter: block = (b, y, 64-x strip). Gather winner rows coalesced,
// stage in XOR-swizzled LDS, write all 64 channel planes coalesced.
// ---------------------------------------------------------------------------
__global__ __launch_bounds__(256) void scatter_kernel(
    const float4* __restrict__ pooled4,   // (P, 64) viewed as float4[P*16]
    const int*    __restrict__ winner,
    float4* __restrict__ out,             // (B, 64, YG, XG) as float4
    int ntx)                              // x tiles = 7
{
    __shared__ int   swn[TILE];
    __shared__ float st[TILE * COUT];     // 16 KB, swizzled

    const int bid  = blockIdx.x;
    const int tx   = bid % ntx;
    const int rest = bid / ntx;
    const int y    = rest % YG;
    const int b    = rest / YG;
    const int x0   = tx * TILE;
    const int tid  = threadIdx.x;

    if (tid < TILE) {
        const int x = x0 + tid;
        swn[tid] = (x < XG) ? winner[(b * YG + y) * XG + x] : -1;
    }
    __syncthreads();

    float4* st4 = (float4*)st;
    #pragma unroll
    for (int i = 0; i < 4; ++i) {
        const int f    = i * 256 + tid;
        const int cell = f >> 4, q = f & 15;
        const int wn   = swn[cell];
        float4 v = make_float4(0.f, 0.f, 0.f, 0.f);
        if (wn >= 0) v = pooled4[(size_t)wn * 16 + q];
        const int qp = q ^ (((cell >> 2) ^ cell) & 15);
        st4[cell * 16 + qp] = v;
    }
    __syncthreads();

    #pragma unroll
    for (int i = 0; i < 4; ++i) {
        const int f   = i * 256 + tid;
        const int ch  = f >> 4, xi4 = f & 15;
        const int x   = x0 + xi4 * 4;
        if (x >= XG) continue;
        const int g = ch >> 2, cl = ch & 3;
        float vals[4];
        #pragma unroll
        for (int r = 0; r < 4; ++r) {
            const int cell = xi4 * 4 + r;
            const int gp = g ^ (((cell >> 2) ^ cell) & 15);
            vals[r] = st[cell * COUT + gp * 4 + cl];
        }
        out[((size_t)(b * COUT + ch) * YG + y) * (XG / 4) + (x >> 2)] =
            make_float4(vals[0], vals[1], vals[2], vals[3]);
    }
}

extern "C" void kernel_launch(void* const* d_in, const int* in_sizes, int n_in,
                              void* d_out, int out_size, void* d_ws, size_t ws_size,
                              hipStream_t stream) {
    const float* pillars = (const float*)d_in[0];
    const int*   coors   = (const int*)d_in[1];
    const int*   npp     = (const int*)d_in[2];
    const float* W1 = (const float*)d_in[4];
    const float* g1 = (const float*)d_in[5];
    const float* b1 = (const float*)d_in[6];
    const float* m1 = (const float*)d_in[7];
    const float* v1 = (const float*)d_in[8];
    const float* W2 = (const float*)d_in[9];
    const float* g2 = (const float*)d_in[10];
    const float* b2 = (const float*)d_in[11];
    const float* m2 = (const float*)d_in[12];
    const float* v2 = (const float*)d_in[13];

    const int P = in_sizes[2];                       // 64000
    const int B = out_size / (COUT * YG * XG);       // 4

    float* pooled = (float*)d_ws;
    int*   winner = (int*)((char*)d_ws + (size_t)COUT * P * sizeof(float));

    // Fragment scratch lives in the tail of d_out (scatter overwrites it last).
    char* fragbase = (char*)d_out + (size_t)out_size * sizeof(float) - 11264;
    unsigned short* w1f = (unsigned short*)fragbase;            // 2048 B
    unsigned short* w2f = (unsigned short*)(fragbase + 2048);   // 8192 B
    float*          bnp = (float*)(fragbase + 10240);           // 1024 B

    precompute_kernel<<<1, 256, 0, stream>>>(
        W1, g1, b1, m1, v1, W2, g2, b2, m2, v2, w1f, w2f, bnp);

    (void)hipMemsetAsync(winner, 0xFF, (size_t)B * YG * XG * sizeof(int), stream);

    pillar_mlp_kernel<<<(P + 3) / 4, 256, 0, stream>>>(
        pillars, coors, npp, w1f, w2f, bnp, pooled, winner, P);

    const int ntx = (XG + TILE - 1) / TILE;          // 7
    scatter_kernel<<<B * YG * ntx, 256, 0, stream>>>(
        (const float4*)pooled, winner, (float4*)d_out, ntx);
}

// Round 5
// 315.170 us; speedup vs baseline: 2.7293x; 1.1024x over previous
//
#include <hip/hip_runtime.h>
#include <math.h>

#define XG 432
#define YG 496
#define NPTS 32
#define COUT 64
#define ROWH 72      // halfwords per LDS h1 row (144 B)
#define TILE 64      // x-positions per scatter block

typedef __attribute__((ext_vector_type(8))) __bf16 bf16x8;
typedef __attribute__((ext_vector_type(2))) __bf16 bf16x2;
typedef __attribute__((ext_vector_type(16))) float f32x16;
typedef __attribute__((ext_vector_type(4))) float f32x4;

union ABFrag { bf16x8 v; unsigned short s[8]; };

__device__ __forceinline__ unsigned short f2bf(float f) {
    unsigned u = __builtin_bit_cast(unsigned, f);
    u = (u + 0x7fffu + ((u >> 16) & 1u)) >> 16;
    return (unsigned short)u;
}

__device__ __forceinline__ unsigned pack_bf16(float a, float b) {
#if __has_builtin(__builtin_amdgcn_cvt_pk_bf16_f32)
    bf16x2 r = __builtin_amdgcn_cvt_pk_bf16_f32(a, b);
    return __builtin_bit_cast(unsigned, r);
#else
    return (unsigned)f2bf(a) | ((unsigned)f2bf(b) << 16);
#endif
}

// ---------------------------------------------------------------------------
// One-block precompute. BN folded into the weights:
//   W1' = W1 * s1 (per out-channel), bias bb1 appended as feature k=6
//   W2' = W2 * s2 (per out-channel), bias bb2 added after max-pool
//   h1 LDS position k' holds channel sigma(k') = (k'&1)*32 + (k'>>1).
// ---------------------------------------------------------------------------
__global__ __launch_bounds__(256) void precompute_kernel(
    const float* __restrict__ W1,
    const float* __restrict__ g1, const float* __restrict__ b1,
    const float* __restrict__ m1, const float* __restrict__ v1,
    const float* __restrict__ W2,
    const float* __restrict__ g2, const float* __restrict__ b2,
    const float* __restrict__ m2, const float* __restrict__ v2,
    unsigned short* __restrict__ w1f,   // [2][64][8]
    unsigned short* __restrict__ w2f,   // [2][4][64][8]
    float* __restrict__ bb2v)           // [64]
{
    const int t = threadIdx.x;
    // W1 fragments (B[k][n], K padded 7->16; k=6 is the BN1 bias row)
    if (t < 128) {
        const int tt = t >> 6, lane = t & 63;
        const int half = lane >> 5, l31 = lane & 31;
        unsigned short vals[8] = {0,0,0,0,0,0,0,0};
        if (half == 0) {
            const int co = tt * 32 + l31;
            const float s1  = g1[co] * rsqrtf(v1[co] + 1e-5f);
            const float bb1 = b1[co] - m1[co] * s1;
            for (int k = 0; k < 6; ++k) vals[k] = f2bf(W1[co * 6 + k] * s1);
            vals[6] = f2bf(bb1);
        }
        for (int j = 0; j < 8; ++j) w1f[(tt * 64 + lane) * 8 + j] = vals[j];
    }
    // BN2 folded bias
    if (t < 64) {
        const float s2 = g2[t] * rsqrtf(v2[t] + 1e-5f);
        bb2v[t] = b2[t] - m2[t] * s2;
    }
    // W2 fragments, s2-scaled, channel-permuted K
    for (int idx = t; idx < 512; idx += 256) {
        const int tt   = idx >> 8;
        const int kt   = (idx >> 6) & 3;
        const int lane = idx & 63;
        const int half = lane >> 5, l31 = lane & 31;
        const int co = tt * 32 + l31;
        const float s2 = g2[co] * rsqrtf(v2[co] + 1e-5f);
        for (int j = 0; j < 8; ++j) {
            const int kp = kt * 16 + half * 8 + j;
            const int ci = ((kp & 1) << 5) | (kp >> 1);   // sigma(kp)
            w2f[((tt * 4 + kt) * 64 + lane) * 8 + j] = f2bf(W2[co * COUT + ci] * s2);
        }
    }
}

// ---------------------------------------------------------------------------
// One wave per pillar, 4 waves/block. MLP1+MLP2 via v_mfma_f32_32x32x16_bf16.
// No __syncthreads: each wave owns its private LDS slab.
// ---------------------------------------------------------------------------
__global__ __launch_bounds__(256) void pillar_mlp_kernel(
    const float* __restrict__ pillars,   // (P, 32, 4)
    const int*   __restrict__ coors,     // (P, 4) : b, x, y, 0
    const int*   __restrict__ npp,       // (P,)
    const unsigned short* __restrict__ w1f,
    const unsigned short* __restrict__ w2f,
    const float* __restrict__ bb2v,
    float* __restrict__ pooled,          // (P, 64)
    int*   __restrict__ winner,          // (B, YG, XG), pre-set to -1
    int P)
{
    __shared__ unsigned int sh1[4][NPTS * (ROWH / 2)];   // 18432 B

    const int w    = threadIdx.x >> 6;
    const int lane = threadIdx.x & 63;
    const int half = lane >> 5;
    const int l31  = lane & 31;
    const int p    = blockIdx.x * 4 + w;
    const int pc   = (p < P) ? p : (P - 1);

    // ---- pre-converted fragments (coalesced dwordx4, L1/L2-hot) ----
    const bf16x8* w2v = (const bf16x8*)w2f;
    bf16x8 b2f[8];
    #pragma unroll
    for (int i = 0; i < 8; ++i) b2f[i] = w2v[i * 64 + lane];
    const bf16x8* w1v = (const bf16x8*)w1f;
    const bf16x8 b1f0 = w1v[lane];
    const bf16x8 b1f1 = w1v[64 + lane];
    const float bb2 = bb2v[lane];        // lane == channel after pooling

    // ---- point load + center reduction ----
    float4 pt = make_float4(0.f, 0.f, 0.f, 0.f);
    if (lane < NPTS) pt = ((const float4*)pillars)[(size_t)pc * NPTS + lane];
    float sx = pt.x, sy = pt.y, sz = pt.z;
    #pragma unroll
    for (int m = 1; m <= 16; m <<= 1) {
        sx += __shfl_xor(sx, m);
        sy += __shfl_xor(sy, m);
        sz += __shfl_xor(sz, m);
    }
    const int   np     = npp[pc];
    const float inv_np = 1.0f / (float)np;
    const float cx = sx * inv_np, cy = sy * inv_np, cz = sz * inv_np;

    const int cb  = coors[pc * 4 + 0];
    const int cxg = coors[pc * 4 + 1];
    const int cyg = coors[pc * 4 + 2];
    const float px = (float)cxg * 0.16f + 0.08f;
    const float py = (float)cyg * 0.16f + (-39.60f);

    // ---- A-fragment for MLP1 (lane = point for lanes 0..31, K pad 16) ----
    ABFrag a1;
    #pragma unroll
    for (int j = 0; j < 8; ++j) a1.s[j] = 0;
    if (half == 0) a1.s[6] = 0x3F80;     // constant-1 bias feature, ALL points
    if (lane < np) {                     // np <= 32
        a1.s[0] = f2bf(pt.z);
        a1.s[1] = f2bf(pt.x - cx);
        a1.s[2] = f2bf(pt.y - cy);
        a1.s[3] = f2bf(pt.z - cz);
        a1.s[4] = f2bf(pt.x - px);
        a1.s[5] = f2bf(pt.y - py);
    }

    // ---- MLP1 (BN1 pre-folded) ----
    f32x16 d0, d1;
    #pragma unroll
    for (int i = 0; i < 16; ++i) { d0[i] = 0.f; d1[i] = 0.f; }
    d0 = __builtin_amdgcn_mfma_f32_32x32x16_bf16(a1.v, b1f0, d0, 0, 0, 0);
    d1 = __builtin_amdgcn_mfma_f32_32x32x16_bf16(a1.v, b1f1, d1, 0, 0, 0);

    // ---- ReLU -> LDS, interleaved channels, packed b32 writes ----
    unsigned int* row = sh1[w];
    #pragma unroll
    for (int r = 0; r < 16; ++r) {
        const int point = (r & 3) + 8 * (r >> 2) + 4 * half;
        row[point * (ROWH / 2) + l31] =
            pack_bf16(fmaxf(d0[r], 0.f), fmaxf(d1[r], 0.f));
    }

    // ---- MLP2: A from own slab (4 ds_read_b128), 8 MFMA ----
    const unsigned short* rowh = (const unsigned short*)sh1[w];
    bf16x8 a2[4];
    #pragma unroll
    for (int kt = 0; kt < 4; ++kt)
        a2[kt] = *(const bf16x8*)(rowh + l31 * ROWH + kt * 16 + half * 8);

    f32x16 c0, c1;
    #pragma unroll
    for (int i = 0; i < 16; ++i) { c0[i] = 0.f; c1[i] = 0.f; }
    #pragma unroll
    for (int kt = 0; kt < 4; ++kt) {
        c0 = __builtin_amdgcn_mfma_f32_32x32x16_bf16(a2[kt], b2f[kt],     c0, 0, 0, 0);
        c1 = __builtin_amdgcn_mfma_f32_32x32x16_bf16(a2[kt], b2f[4 + kt], c1, 0, 0, 0);
    }

    // ---- max-pool (s2 folded into W2; bias added once after) ----
    float mx0 = -INFINITY, mx1 = -INFINITY;
    #pragma unroll
    for (int r = 0; r < 16; ++r) {
        mx0 = fmaxf(mx0, c0[r]);
        mx1 = fmaxf(mx1, c1[r]);
    }
    mx0 = fmaxf(mx0, __shfl_xor(mx0, 32));
    mx1 = fmaxf(mx1, __shfl_xor(mx1, 32));

    if (p < P) {
        pooled[(size_t)p * COUT + lane] = (half ? mx1 : mx0) + bb2;
        if (lane == 0)
            atomicMax(&winner[cb * (YG * XG) + cyg * XG + cxg], p);
    }
}

// ---------------------------------------------------------------------------
// Tile scatter: block = (b, y, 64-x strip). Gather winner rows coalesced,
// stage in XOR-swizzled LDS, write all 64 channel planes coalesced
// (non-temporal: 219 MB streamed once, keep L2 for the gathers).
// ---------------------------------------------------------------------------
__global__ __launch_bounds__(256) void scatter_kernel(
    const float4* __restrict__ pooled4,   // (P, 64) viewed as float4[P*16]
    const int*    __restrict__ winner,
    f32x4* __restrict__ out,              // (B, 64, YG, XG) as float4
    int ntx)                              // x tiles = 7
{
    __shared__ int   swn[TILE];
    __shared__ float st[TILE * COUT];     // 16 KB, swizzled

    const int bid  = blockIdx.x;
    const int tx   = bid % ntx;
    const int rest = bid / ntx;
    const int y    = rest % YG;
    const int b    = rest / YG;
    const int x0   = tx * TILE;
    const int tid  = threadIdx.x;

    if (tid < TILE) {
        const int x = x0 + tid;
        swn[tid] = (x < XG) ? winner[(b * YG + y) * XG + x] : -1;
    }
    __syncthreads();

    float4* st4 = (float4*)st;
    #pragma unroll
    for (int i = 0; i < 4; ++i) {
        const int f    = i * 256 + tid;
        const int cell = f >> 4, q = f & 15;
        const int wn   = swn[cell];
        float4 v = make_float4(0.f, 0.f, 0.f, 0.f);
        if (wn >= 0) v = pooled4[(size_t)wn * 16 + q];
        const int qp = q ^ (((cell >> 2) ^ cell) & 15);
        st4[cell * 16 + qp] = v;
    }
    __syncthreads();

    #pragma unroll
    for (int i = 0; i < 4; ++i) {
        const int f   = i * 256 + tid;
        const int ch  = f >> 4, xi4 = f & 15;
        const int x   = x0 + xi4 * 4;
        if (x >= XG) continue;
        const int g = ch >> 2, cl = ch & 3;
        f32x4 vals;
        #pragma unroll
        for (int r = 0; r < 4; ++r) {
            const int cell = xi4 * 4 + r;
            const int gp = g ^ (((cell >> 2) ^ cell) & 15);
            vals[r] = st[cell * COUT + gp * 4 + cl];
        }
        __builtin_nontemporal_store(vals,
            &out[((size_t)(b * COUT + ch) * YG + y) * (XG / 4) + (x >> 2)]);
    }
}

extern "C" void kernel_launch(void* const* d_in, const int* in_sizes, int n_in,
                              void* d_out, int out_size, void* d_ws, size_t ws_size,
                              hipStream_t stream) {
    const float* pillars = (const float*)d_in[0];
    const int*   coors   = (const int*)d_in[1];
    const int*   npp     = (const int*)d_in[2];
    const float* W1 = (const float*)d_in[4];
    const float* g1 = (const float*)d_in[5];
    const float* b1 = (const float*)d_in[6];
    const float* m1 = (const float*)d_in[7];
    const float* v1 = (const float*)d_in[8];
    const float* W2 = (const float*)d_in[9];
    const float* g2 = (const float*)d_in[10];
    const float* b2 = (const float*)d_in[11];
    const float* m2 = (const float*)d_in[12];
    const float* v2 = (const float*)d_in[13];

    const int P = in_sizes[2];                       // 64000
    const int B = out_size / (COUT * YG * XG);       // 4

    float* pooled = (float*)d_ws;
    int*   winner = (int*)((char*)d_ws + (size_t)COUT * P * sizeof(float));

    // Fragment scratch lives in the tail of d_out (scatter overwrites it last).
    char* fragbase = (char*)d_out + (size_t)out_size * sizeof(float) - 11264;
    unsigned short* w1f  = (unsigned short*)fragbase;            // 2048 B
    unsigned short* w2f  = (unsigned short*)(fragbase + 2048);   // 8192 B
    float*          bb2v = (float*)(fragbase + 10240);           // 256 B

    precompute_kernel<<<1, 256, 0, stream>>>(
        W1, g1, b1, m1, v1, W2, g2, b2, m2, v2, w1f, w2f, bb2v);

    (void)hipMemsetAsync(winner, 0xFF, (size_t)B * YG * XG * sizeof(int), stream);

    pillar_mlp_kernel<<<(P + 3) / 4, 256, 0, stream>>>(
        pillars, coors, npp, w1f, w2f, bb2v, pooled, winner, P);

    const int ntx = (XG + TILE - 1) / TILE;          // 7
    scatter_kernel<<<B * YG * ntx, 256, 0, stream>>>(
        (const float4*)pooled, winner, (f32x4*)d_out, ntx);
}

// Round 6
// 314.327 us; speedup vs baseline: 2.7367x; 1.0027x over previous
//
#include <hip/hip_runtime.h>
#include <math.h>

#define XG 432
#define YG 496
#define NPTS 32
#define COUT 64
#define ROWH 72      // halfwords per LDS h1 row (144 B)
#define TILE 64      // x-positions per scatter block

typedef __attribute__((ext_vector_type(8))) __bf16 bf16x8;
typedef __attribute__((ext_vector_type(2))) __bf16 bf16x2;
typedef __attribute__((ext_vector_type(16))) float f32x16;
typedef __attribute__((ext_vector_type(4))) float f32x4;

union ABFrag { bf16x8 v; unsigned short s[8]; unsigned u[4]; };

__device__ __forceinline__ unsigned short f2bf(float f) {
    unsigned u = __builtin_bit_cast(unsigned, f);
    u = (u + 0x7fffu + ((u >> 16) & 1u)) >> 16;
    return (unsigned short)u;
}

__device__ __forceinline__ unsigned pack_bf16(float a, float b) {
#if __has_builtin(__builtin_amdgcn_cvt_pk_bf16_f32)
    bf16x2 r = __builtin_amdgcn_cvt_pk_bf16_f32(a, b);
    return __builtin_bit_cast(unsigned, r);
#else
    return (unsigned)f2bf(a) | ((unsigned)f2bf(b) << 16);
#endif
}

// ---------------------------------------------------------------------------
// Precompute (block 0) + winner=-1 init (all blocks). BN folded into weights:
//   W1' = W1 * s1, bias bb1 appended as feature k=6 (K padded 7->16)
//   W2' = W2 * s2, bias bb2 added after max-pool (exact: s2 const per channel)
//   h1 LDS position k' holds channel sigma(k') = (k'&1)*32 + (k'>>1).
// ---------------------------------------------------------------------------
__global__ __launch_bounds__(256) void precompute_kernel(
    const float* __restrict__ W1,
    const float* __restrict__ g1, const float* __restrict__ b1,
    const float* __restrict__ m1, const float* __restrict__ v1,
    const float* __restrict__ W2,
    const float* __restrict__ g2, const float* __restrict__ b2,
    const float* __restrict__ m2, const float* __restrict__ v2,
    unsigned short* __restrict__ w1f,   // [2][64][8]
    unsigned short* __restrict__ w2f,   // [2][4][64][8]
    float* __restrict__ bb2v,           // [64]
    int4* __restrict__ winner4, int nwin4)
{
    const int gid = blockIdx.x * 256 + threadIdx.x;
    if (gid < nwin4) winner4[gid] = make_int4(-1, -1, -1, -1);
    if (blockIdx.x != 0) return;

    const int t = threadIdx.x;
    // W1 fragments (B[k][n], K padded 7->16; k=6 is the BN1 bias row)
    if (t < 128) {
        const int tt = t >> 6, lane = t & 63;
        const int half = lane >> 5, l31 = lane & 31;
        unsigned short vals[8] = {0,0,0,0,0,0,0,0};
        if (half == 0) {
            const int co = tt * 32 + l31;
            const float s1  = g1[co] * rsqrtf(v1[co] + 1e-5f);
            const float bb1 = b1[co] - m1[co] * s1;
            for (int k = 0; k < 6; ++k) vals[k] = f2bf(W1[co * 6 + k] * s1);
            vals[6] = f2bf(bb1);
        }
        for (int j = 0; j < 8; ++j) w1f[(tt * 64 + lane) * 8 + j] = vals[j];
    }
    // BN2 folded bias
    if (t < 64) {
        const float s2 = g2[t] * rsqrtf(v2[t] + 1e-5f);
        bb2v[t] = b2[t] - m2[t] * s2;
    }
    // W2 fragments, s2-scaled, channel-permuted K
    for (int idx = t; idx < 512; idx += 256) {
        const int tt   = idx >> 8;
        const int kt   = (idx >> 6) & 3;
        const int lane = idx & 63;
        const int half = lane >> 5, l31 = lane & 31;
        const int co = tt * 32 + l31;
        const float s2 = g2[co] * rsqrtf(v2[co] + 1e-5f);
        for (int j = 0; j < 8; ++j) {
            const int kp = kt * 16 + half * 8 + j;
            const int ci = ((kp & 1) << 5) | (kp >> 1);   // sigma(kp)
            w2f[((tt * 4 + kt) * 64 + lane) * 8 + j] = f2bf(W2[co * COUT + ci] * s2);
        }
    }
}

// ---------------------------------------------------------------------------
// One wave per pillar, 4 waves/block. Register-pressure-shaped:
// W2 fragments loaded per N-tile AFTER MLP1 so peak (VGPR+AGPR) stays low.
// ---------------------------------------------------------------------------
__global__ __launch_bounds__(256) void pillar_mlp_kernel(
    const float* __restrict__ pillars,   // (P, 32, 4)
    const int*   __restrict__ coors,     // (P, 4) : b, x, y, 0
    const int*   __restrict__ npp,       // (P,)
    const unsigned short* __restrict__ w1f,
    const unsigned short* __restrict__ w2f,
    const float* __restrict__ bb2v,
    float* __restrict__ pooled,          // (P, 64)
    int*   __restrict__ winner,          // (B, YG, XG), pre-set to -1
    int P)
{
    __shared__ unsigned int sh1[4][NPTS * (ROWH / 2)];   // 18432 B

    const int w    = threadIdx.x >> 6;
    const int lane = threadIdx.x & 63;
    const int half = lane >> 5;
    const int l31  = lane & 31;
    const int p    = blockIdx.x * 4 + w;
    const int pc   = (p < P) ? p : (P - 1);

    // ---- early independent loads ----
    float4 pt = make_float4(0.f, 0.f, 0.f, 0.f);
    if (lane < NPTS) pt = ((const float4*)pillars)[(size_t)pc * NPTS + lane];
    const int  np = npp[pc];
    const int4 cr = ((const int4*)coors)[pc];
    const bf16x8* w1v = (const bf16x8*)w1f;
    const bf16x8 b1f0 = w1v[lane];
    const bf16x8 b1f1 = w1v[64 + lane];

    // ---- per-pillar xyz mean over 32 points ----
    float sx = pt.x, sy = pt.y, sz = pt.z;
    #pragma unroll
    for (int m = 1; m <= 16; m <<= 1) {
        sx += __shfl_xor(sx, m);
        sy += __shfl_xor(sy, m);
        sz += __shfl_xor(sz, m);
    }
    const float inv_np = 1.0f / (float)np;
    const float cx = sx * inv_np, cy = sy * inv_np, cz = sz * inv_np;
    const float px = (float)cr.y * 0.16f + 0.08f;
    const float py = (float)cr.z * 0.16f + (-39.60f);

    // ---- A-fragment: 4 packed dwords; lane<np covers (half==0 && valid) ----
    const bool on = (lane < np);
    ABFrag a1;
    a1.u[0] = on ? pack_bf16(pt.z,      pt.x - cx) : 0u;
    a1.u[1] = on ? pack_bf16(pt.y - cy, pt.z - cz) : 0u;
    a1.u[2] = on ? pack_bf16(pt.x - px, pt.y - py) : 0u;
    a1.u[3] = (half == 0) ? 0x00003F80u : 0u;   // bias feature = 1.0, ALL points

    // ---- MLP1 (BN1 pre-folded) ----
    f32x16 d0, d1;
    #pragma unroll
    for (int i = 0; i < 16; ++i) { d0[i] = 0.f; d1[i] = 0.f; }
    d0 = __builtin_amdgcn_mfma_f32_32x32x16_bf16(a1.v, b1f0, d0, 0, 0, 0);
    d1 = __builtin_amdgcn_mfma_f32_32x32x16_bf16(a1.v, b1f1, d1, 0, 0, 0);

    // ---- ReLU -> LDS, interleaved channels, packed b32 writes ----
    unsigned int* row = sh1[w];
    #pragma unroll
    for (int r = 0; r < 16; ++r) {
        const int point = (r & 3) + 8 * (r >> 2) + 4 * half;
        row[point * (ROWH / 2) + l31] =
            pack_bf16(fmaxf(d0[r], 0.f), fmaxf(d1[r], 0.f));
    }

    // ---- MLP2 A-fragments from own slab (4 ds_read_b128) ----
    const unsigned short* rowh = (const unsigned short*)sh1[w];
    bf16x8 a2[4];
    #pragma unroll
    for (int kt = 0; kt < 4; ++kt)
        a2[kt] = *(const bf16x8*)(rowh + l31 * ROWH + kt * 16 + half * 8);

    const bf16x8* w2v = (const bf16x8*)w2f;
    float mx[2];
    #pragma unroll
    for (int tile = 0; tile < 2; ++tile) {
        // load this tile's W2 fragments now (16 VGPRs live, not 32)
        bf16x8 bt0 = w2v[(tile * 4 + 0) * 64 + lane];
        bf16x8 bt1 = w2v[(tile * 4 + 1) * 64 + lane];
        bf16x8 bt2 = w2v[(tile * 4 + 2) * 64 + lane];
        bf16x8 bt3 = w2v[(tile * 4 + 3) * 64 + lane];
        f32x16 c;
        #pragma unroll
        for (int i = 0; i < 16; ++i) c[i] = 0.f;
        c = __builtin_amdgcn_mfma_f32_32x32x16_bf16(a2[0], bt0, c, 0, 0, 0);
        c = __builtin_amdgcn_mfma_f32_32x32x16_bf16(a2[1], bt1, c, 0, 0, 0);
        c = __builtin_amdgcn_mfma_f32_32x32x16_bf16(a2[2], bt2, c, 0, 0, 0);
        c = __builtin_amdgcn_mfma_f32_32x32x16_bf16(a2[3], bt3, c, 0, 0, 0);
        // max-pool (fmax tree -> v_max3)
        float m01 = fmaxf(c[0], c[1]),   m23 = fmaxf(c[2], c[3]);
        float m45 = fmaxf(c[4], c[5]),   m67 = fmaxf(c[6], c[7]);
        float m89 = fmaxf(c[8], c[9]),   mab = fmaxf(c[10], c[11]);
        float mcd = fmaxf(c[12], c[13]), mef = fmaxf(c[14], c[15]);
        float q0 = fmaxf(fmaxf(m01, m23), fmaxf(m45, m67));
        float q1 = fmaxf(fmaxf(m89, mab), fmaxf(mcd, mef));
        mx[tile] = fmaxf(q0, q1);
    }
    mx[0] = fmaxf(mx[0], __shfl_xor(mx[0], 32));
    mx[1] = fmaxf(mx[1], __shfl_xor(mx[1], 32));

    if (p < P) {
        pooled[(size_t)p * COUT + lane] = (half ? mx[1] : mx[0]) + bb2v[lane];
        if (lane == 0)
            atomicMax(&winner[cr.x * (YG * XG) + cr.z * XG + cr.y], p);
    }
}

// ---------------------------------------------------------------------------
// Tile scatter: block = (b, y, 64-x strip). Gather winner rows coalesced,
// stage in XOR-swizzled LDS, write all 64 channel planes coalesced
// (non-temporal: 219 MB streamed once, keep L2 clean for the harness fill).
// ---------------------------------------------------------------------------
__global__ __launch_bounds__(256) void scatter_kernel(
    const float4* __restrict__ pooled4,   // (P, 64) viewed as float4[P*16]
    const int*    __restrict__ winner,
    f32x4* __restrict__ out,              // (B, 64, YG, XG) as float4
    int ntx)                              // x tiles = 7
{
    __shared__ int   swn[TILE];
    __shared__ float st[TILE * COUT];     // 16 KB, swizzled

    const int bid  = blockIdx.x;
    const int tx   = bid % ntx;
    const int rest = bid / ntx;
    const int y    = rest % YG;
    const int b    = rest / YG;
    const int x0   = tx * TILE;
    const int tid  = threadIdx.x;

    if (tid < TILE) {
        const int x = x0 + tid;
        swn[tid] = (x < XG) ? winner[(b * YG + y) * XG + x] : -1;
    }
    __syncthreads();

    float4* st4 = (float4*)st;
    #pragma unroll
    for (int i = 0; i < 4; ++i) {
        const int f    = i * 256 + tid;
        const int cell = f >> 4, q = f & 15;
        const int wn   = swn[cell];
        float4 v = make_float4(0.f, 0.f, 0.f, 0.f);
        if (wn >= 0) v = pooled4[(size_t)wn * 16 + q];
        const int qp = q ^ (((cell >> 2) ^ cell) & 15);
        st4[cell * 16 + qp] = v;
    }
    __syncthreads();

    #pragma unroll
    for (int i = 0; i < 4; ++i) {
        const int f   = i * 256 + tid;
        const int ch  = f >> 4, xi4 = f & 15;
        const int x   = x0 + xi4 * 4;
        if (x >= XG) continue;
        const int g = ch >> 2, cl = ch & 3;
        f32x4 vals;
        #pragma unroll
        for (int r = 0; r < 4; ++r) {
            const int cell = xi4 * 4 + r;
            const int gp = g ^ (((cell >> 2) ^ cell) & 15);
            vals[r] = st[cell * COUT + gp * 4 + cl];
        }
        __builtin_nontemporal_store(vals,
            &out[((size_t)(b * COUT + ch) * YG + y) * (XG / 4) + (x >> 2)]);
    }
}

extern "C" void kernel_launch(void* const* d_in, const int* in_sizes, int n_in,
                              void* d_out, int out_size, void* d_ws, size_t ws_size,
                              hipStream_t stream) {
    const float* pillars = (const float*)d_in[0];
    const int*   coors   = (const int*)d_in[1];
    const int*   npp     = (const int*)d_in[2];
    const float* W1 = (const float*)d_in[4];
    const float* g1 = (const float*)d_in[5];
    const float* b1 = (const float*)d_in[6];
    const float* m1 = (const float*)d_in[7];
    const float* v1 = (const float*)d_in[8];
    const float* W2 = (const float*)d_in[9];
    const float* g2 = (const float*)d_in[10];
    const float* b2 = (const float*)d_in[11];
    const float* m2 = (const float*)d_in[12];
    const float* v2 = (const float*)d_in[13];

    const int P = in_sizes[2];                       // 64000
    const int B = out_size / (COUT * YG * XG);       // 4

    float* pooled = (float*)d_ws;
    int*   winner = (int*)((char*)d_ws + (size_t)COUT * P * sizeof(float));

    // Fragment scratch lives in the tail of d_out (scatter overwrites it last).
    char* fragbase = (char*)d_out + (size_t)out_size * sizeof(float) - 11264;
    unsigned short* w1f  = (unsigned short*)fragbase;            // 2048 B
    unsigned short* w2f  = (unsigned short*)(fragbase + 2048);   // 8192 B
    float*          bb2v = (float*)(fragbase + 10240);           // 256 B

    const int nwin4 = (B * YG * XG) / 4;             // 214272
    precompute_kernel<<<(nwin4 + 255) / 256, 256, 0, stream>>>(
        W1, g1, b1, m1, v1, W2, g2, b2, m2, v2, w1f, w2f, bb2v,
        (int4*)winner, nwin4);

    pillar_mlp_kernel<<<(P + 3) / 4, 256, 0, stream>>>(
        pillars, coors, npp, w1f, w2f, bb2v, pooled, winner, P);

    const int ntx = (XG + TILE - 1) / TILE;          // 7
    scatter_kernel<<<B * YG * ntx, 256, 0, stream>>>(
        (const float4*)pooled, winner, (f32x4*)d_out, ntx);
}

// Round 8
// 308.669 us; speedup vs baseline: 2.7868x; 1.0183x over previous
//
#include <hip/hip_runtime.h>
#include <math.h>

#define XG 432
#define YG 496
#define NPTS 32
#define COUT 64
#define ROWH 72      // halfwords per LDS h1 row (144 B)
#define TILE 64      // x-positions per scatter block

typedef __attribute__((ext_vector_type(8))) __bf16 bf16x8;
typedef __attribute__((ext_vector_type(2))) __bf16 bf16x2;
typedef __attribute__((ext_vector_type(16))) float f32x16;
typedef __attribute__((ext_vector_type(4))) float f32x4;

union ABFrag { bf16x8 v; unsigned short s[8]; unsigned u[4]; };

__device__ __forceinline__ unsigned short f2bf(float f) {
    unsigned u = __builtin_bit_cast(unsigned, f);
    u = (u + 0x7fffu + ((u >> 16) & 1u)) >> 16;
    return (unsigned short)u;
}

__device__ __forceinline__ unsigned pack_bf16(float a, float b) {
#if __has_builtin(__builtin_amdgcn_cvt_pk_bf16_f32)
    bf16x2 r = __builtin_amdgcn_cvt_pk_bf16_f32(a, b);
    return __builtin_bit_cast(unsigned, r);
#else
    return (unsigned)f2bf(a) | ((unsigned)f2bf(b) << 16);
#endif
}

// ---------------------------------------------------------------------------
// Precompute (block 0) + winner=-1 init (all blocks). BN folded into weights:
//   W1' = W1 * s1, bias bb1 appended as feature k=6 (K padded 7->16)
//   W2' = W2 * s2, bias bb2 added after max-pool (exact: s2 const per channel)
//   h1 LDS position k' holds channel sigma(k') = (k'&1)*32 + (k'>>1).
// ---------------------------------------------------------------------------
__global__ __launch_bounds__(256) void precompute_kernel(
    const float* __restrict__ W1,
    const float* __restrict__ g1, const float* __restrict__ b1,
    const float* __restrict__ m1, const float* __restrict__ v1,
    const float* __restrict__ W2,
    const float* __restrict__ g2, const float* __restrict__ b2,
    const float* __restrict__ m2, const float* __restrict__ v2,
    unsigned short* __restrict__ w1f,   // [2][64][8]
    unsigned short* __restrict__ w2f,   // [2][4][64][8]
    float* __restrict__ bb2v,           // [64]
    int4* __restrict__ winner4, int nwin4)
{
    const int gid = blockIdx.x * 256 + threadIdx.x;
    if (gid < nwin4) winner4[gid] = make_int4(-1, -1, -1, -1);
    if (blockIdx.x != 0) return;

    const int t = threadIdx.x;
    if (t < 128) {
        const int tt = t >> 6, lane = t & 63;
        const int half = lane >> 5, l31 = lane & 31;
        unsigned short vals[8] = {0,0,0,0,0,0,0,0};
        if (half == 0) {
            const int co = tt * 32 + l31;
            const float s1  = g1[co] * rsqrtf(v1[co] + 1e-5f);
            const float bb1 = b1[co] - m1[co] * s1;
            for (int k = 0; k < 6; ++k) vals[k] = f2bf(W1[co * 6 + k] * s1);
            vals[6] = f2bf(bb1);
        }
        for (int j = 0; j < 8; ++j) w1f[(tt * 64 + lane) * 8 + j] = vals[j];
    }
    if (t < 64) {
        const float s2 = g2[t] * rsqrtf(v2[t] + 1e-5f);
        bb2v[t] = b2[t] - m2[t] * s2;
    }
    for (int idx = t; idx < 512; idx += 256) {
        const int tt   = idx >> 8;
        const int kt   = (idx >> 6) & 3;
        const int lane = idx & 63;
        const int half = lane >> 5, l31 = lane & 31;
        const int co = tt * 32 + l31;
        const float s2 = g2[co] * rsqrtf(v2[co] + 1e-5f);
        for (int j = 0; j < 8; ++j) {
            const int kp = kt * 16 + half * 8 + j;
            const int ci = ((kp & 1) << 5) | (kp >> 1);   // sigma(kp)
            w2f[((tt * 4 + kt) * 64 + lane) * 8 + j] = f2bf(W2[co * COUT + ci] * s2);
        }
    }
}

// ---------------------------------------------------------------------------
// TWO pillars per wave (adjacent => one contiguous float4 point load covers
// both). Two independent dependency chains per wave for latency hiding;
// W1/W2 fragment loads amortized over 2 pillars. 4 waves/block = 8 pillars.
// NOTE: all __shfl_* are executed UNCONDITIONALLY (convergent) and only the
// result is selected per-lane — shuffles inside divergent ternaries are UB.
// ---------------------------------------------------------------------------
__global__ __launch_bounds__(256) void pillar_mlp_kernel(
    const float* __restrict__ pillars,   // (P, 32, 4)
    const int*   __restrict__ coors,     // (P, 4) : b, x, y, 0
    const int*   __restrict__ npp,       // (P,)
    const unsigned short* __restrict__ w1f,
    const unsigned short* __restrict__ w2f,
    const float* __restrict__ bb2v,
    float* __restrict__ pooled,          // (P, 64)
    int*   __restrict__ winner,          // (B, YG, XG), pre-set to -1
    int P)
{
    __shared__ unsigned int sh1[8][NPTS * (ROWH / 2)];   // 36864 B

    const int w    = threadIdx.x >> 6;
    const int lane = threadIdx.x & 63;
    const int half = lane >> 5;
    const int l31  = lane & 31;
    const int pa   = blockIdx.x * 8 + w * 2;             // pillar A
    const int pb   = pa + 1;                             // pillar B
    const int pac  = (pb < P) ? pa : (P >= 2 ? P - 2 : 0);

    // ---- early independent loads: 64 points = pillars A+B contiguous ----
    const float4 pt = ((const float4*)pillars)[(size_t)pac * NPTS + lane];
    const int    np_my = npp[pac + half];                // my pillar's count
    const int4   crA = ((const int4*)coors)[pac];
    const int4   crB = ((const int4*)coors)[pac + 1];
    const bf16x8* w1v = (const bf16x8*)w1f;
    const bf16x8 b1f0 = w1v[lane];
    const bf16x8 b1f1 = w1v[64 + lane];

    // ---- per-half (= per-pillar) xyz mean over 32 points ----
    float sx = pt.x, sy = pt.y, sz = pt.z;
    #pragma unroll
    for (int m = 1; m <= 16; m <<= 1) {
        sx += __shfl_xor(sx, m);
        sy += __shfl_xor(sy, m);
        sz += __shfl_xor(sz, m);
    }
    const float inv_np = 1.0f / (float)np_my;
    const float cx = sx * inv_np, cy = sy * inv_np, cz = sz * inv_np;
    const int   mygx = half ? crB.y : crA.y;
    const int   mygy = half ? crB.z : crA.z;
    const float px = (float)mygx * 0.16f + 0.08f;
    const float py = (float)mygy * 0.16f + (-39.60f);

    // ---- per-lane features of OWN pillar (point l31), packed bf16 ----
    const bool on = (l31 < np_my);
    const unsigned f0 = on ? pack_bf16(pt.z,      pt.x - cx) : 0u;
    const unsigned f1 = on ? pack_bf16(pt.y - cy, pt.z - cz) : 0u;
    const unsigned f2 = on ? pack_bf16(pt.x - px, pt.y - py) : 0u;

    // ---- cross-half copies: shuffles OUTSIDE any divergent select ----
    const unsigned g0 = __shfl_xor(f0, 32);
    const unsigned g1 = __shfl_xor(f1, 32);
    const unsigned g2 = __shfl_xor(f2, 32);

    // ---- assemble A-fragments: aA from half0 lanes, aB from swapped ----
    ABFrag aA, aB;
    aA.u[0] = half ? 0u : f0;
    aA.u[1] = half ? 0u : f1;
    aA.u[2] = half ? 0u : f2;
    aA.u[3] = half ? 0u : 0x00003F80u;   // bias feature = 1.0 (k=6), all rows
    aB.u[0] = half ? 0u : g0;
    aB.u[1] = half ? 0u : g1;
    aB.u[2] = half ? 0u : g2;
    aB.u[3] = aA.u[3];

    // ---- MLP1 (BN1 pre-folded): 2 MFMA per pillar ----
    f32x16 z;
    #pragma unroll
    for (int i = 0; i < 16; ++i) z[i] = 0.f;

    unsigned int* rowA = sh1[w * 2];
    unsigned int* rowB = sh1[w * 2 + 1];
    {
        f32x16 dA0 = __builtin_amdgcn_mfma_f32_32x32x16_bf16(aA.v, b1f0, z, 0, 0, 0);
        f32x16 dA1 = __builtin_amdgcn_mfma_f32_32x32x16_bf16(aA.v, b1f1, z, 0, 0, 0);
        #pragma unroll
        for (int r = 0; r < 16; ++r) {
            const int point = (r & 3) + 8 * (r >> 2) + 4 * half;
            rowA[point * (ROWH / 2) + l31] =
                pack_bf16(fmaxf(dA0[r], 0.f), fmaxf(dA1[r], 0.f));
        }
    }
    {
        f32x16 dB0 = __builtin_amdgcn_mfma_f32_32x32x16_bf16(aB.v, b1f0, z, 0, 0, 0);
        f32x16 dB1 = __builtin_amdgcn_mfma_f32_32x32x16_bf16(aB.v, b1f1, z, 0, 0, 0);
        #pragma unroll
        for (int r = 0; r < 16; ++r) {
            const int point = (r & 3) + 8 * (r >> 2) + 4 * half;
            rowB[point * (ROWH / 2) + l31] =
                pack_bf16(fmaxf(dB0[r], 0.f), fmaxf(dB1[r], 0.f));
        }
    }

    // ---- MLP2 A-fragments from the two slabs (8 ds_read_b128) ----
    const unsigned short* rhA = (const unsigned short*)rowA;
    const unsigned short* rhB = (const unsigned short*)rowB;
    bf16x8 a2A[4], a2B[4];
    #pragma unroll
    for (int kt = 0; kt < 4; ++kt) {
        a2A[kt] = *(const bf16x8*)(rhA + l31 * ROWH + kt * 16 + half * 8);
        a2B[kt] = *(const bf16x8*)(rhB + l31 * ROWH + kt * 16 + half * 8);
    }

    // ---- MLP2: W2 fragments shared by both pillars; 16 MFMA total ----
    const bf16x8* w2v = (const bf16x8*)w2f;
    float mxA[2], mxB[2];
    #pragma unroll
    for (int tile = 0; tile < 2; ++tile) {
        bf16x8 bt0 = w2v[(tile * 4 + 0) * 64 + lane];
        bf16x8 bt1 = w2v[(tile * 4 + 1) * 64 + lane];
        bf16x8 bt2 = w2v[(tile * 4 + 2) * 64 + lane];
        bf16x8 bt3 = w2v[(tile * 4 + 3) * 64 + lane];
        f32x16 cA = z, cB = z;
        cA = __builtin_amdgcn_mfma_f32_32x32x16_bf16(a2A[0], bt0, cA, 0, 0, 0);
        cB = __builtin_amdgcn_mfma_f32_32x32x16_bf16(a2B[0], bt0, cB, 0, 0, 0);
        cA = __builtin_amdgcn_mfma_f32_32x32x16_bf16(a2A[1], bt1, cA, 0, 0, 0);
        cB = __builtin_amdgcn_mfma_f32_32x32x16_bf16(a2B[1], bt1, cB, 0, 0, 0);
        cA = __builtin_amdgcn_mfma_f32_32x32x16_bf16(a2A[2], bt2, cA, 0, 0, 0);
        cB = __builtin_amdgcn_mfma_f32_32x32x16_bf16(a2B[2], bt2, cB, 0, 0, 0);
        cA = __builtin_amdgcn_mfma_f32_32x32x16_bf16(a2A[3], bt3, cA, 0, 0, 0);
        cB = __builtin_amdgcn_mfma_f32_32x32x16_bf16(a2B[3], bt3, cB, 0, 0, 0);
        float a0 = fmaxf(fmaxf(fmaxf(cA[0], cA[1]), fmaxf(cA[2], cA[3])),
                         fmaxf(fmaxf(cA[4], cA[5]), fmaxf(cA[6], cA[7])));
        float a1 = fmaxf(fmaxf(fmaxf(cA[8], cA[9]), fmaxf(cA[10], cA[11])),
                         fmaxf(fmaxf(cA[12], cA[13]), fmaxf(cA[14], cA[15])));
        mxA[tile] = fmaxf(a0, a1);
        float b0 = fmaxf(fmaxf(fmaxf(cB[0], cB[1]), fmaxf(cB[2], cB[3])),
                         fmaxf(fmaxf(cB[4], cB[5]), fmaxf(cB[6], cB[7])));
        float b1_ = fmaxf(fmaxf(fmaxf(cB[8], cB[9]), fmaxf(cB[10], cB[11])),
                          fmaxf(fmaxf(cB[12], cB[13]), fmaxf(cB[14], cB[15])));
        mxB[tile] = fmaxf(b0, b1_);
    }
    mxA[0] = fmaxf(mxA[0], __shfl_xor(mxA[0], 32));
    mxA[1] = fmaxf(mxA[1], __shfl_xor(mxA[1], 32));
    mxB[0] = fmaxf(mxB[0], __shfl_xor(mxB[0], 32));
    mxB[1] = fmaxf(mxB[1], __shfl_xor(mxB[1], 32));

    if (pb < P) {
        const float bb2 = bb2v[lane];    // lane == channel
        pooled[(size_t)pa * COUT + lane] = (half ? mxA[1] : mxA[0]) + bb2;
        pooled[(size_t)pb * COUT + lane] = (half ? mxB[1] : mxB[0]) + bb2;
        if (lane == 0)
            atomicMax(&winner[crA.x * (YG * XG) + crA.z * XG + crA.y], pa);
        if (lane == 32)
            atomicMax(&winner[crB.x * (YG * XG) + crB.z * XG + crB.y], pb);
    }
}

// ---------------------------------------------------------------------------
// Tile scatter (unchanged for attribution): gather winner rows, stage in
// XOR-swizzled LDS, stream all 64 channel planes non-temporally.
// ---------------------------------------------------------------------------
__global__ __launch_bounds__(256) void scatter_kernel(
    const float4* __restrict__ pooled4,   // (P, 64) viewed as float4[P*16]
    const int*    __restrict__ winner,
    f32x4* __restrict__ out,              // (B, 64, YG, XG) as float4
    int ntx)                              // x tiles = 7
{
    __shared__ int   swn[TILE];
    __shared__ float st[TILE * COUT];     // 16 KB, swizzled

    const int bid  = blockIdx.x;
    const int tx   = bid % ntx;
    const int rest = bid / ntx;
    const int y    = rest % YG;
    const int b    = rest / YG;
    const int x0   = tx * TILE;
    const int tid  = threadIdx.x;

    if (tid < TILE) {
        const int x = x0 + tid;
        swn[tid] = (x < XG) ? winner[(b * YG + y) * XG + x] : -1;
    }
    __syncthreads();

    float4* st4 = (float4*)st;
    #pragma unroll
    for (int i = 0; i < 4; ++i) {
        const int f    = i * 256 + tid;
        const int cell = f >> 4, q = f & 15;
        const int wn   = swn[cell];
        float4 v = make_float4(0.f, 0.f, 0.f, 0.f);
        if (wn >= 0) v = pooled4[(size_t)wn * 16 + q];
        const int qp = q ^ (((cell >> 2) ^ cell) & 15);
        st4[cell * 16 + qp] = v;
    }
    __syncthreads();

    #pragma unroll
    for (int i = 0; i < 4; ++i) {
        const int f   = i * 256 + tid;
        const int ch  = f >> 4, xi4 = f & 15;
        const int x   = x0 + xi4 * 4;
        if (x >= XG) continue;
        const int g = ch >> 2, cl = ch & 3;
        f32x4 vals;
        #pragma unroll
        for (int r = 0; r < 4; ++r) {
            const int cell = xi4 * 4 + r;
            const int gp = g ^ (((cell >> 2) ^ cell) & 15);
            vals[r] = st[cell * COUT + gp * 4 + cl];
        }
        __builtin_nontemporal_store(vals,
            &out[((size_t)(b * COUT + ch) * YG + y) * (XG / 4) + (x >> 2)]);
    }
}

extern "C" void kernel_launch(void* const* d_in, const int* in_sizes, int n_in,
                              void* d_out, int out_size, void* d_ws, size_t ws_size,
                              hipStream_t stream) {
    const float* pillars = (const float*)d_in[0];
    const int*   coors   = (const int*)d_in[1];
    const int*   npp     = (const int*)d_in[2];
    const float* W1 = (const float*)d_in[4];
    const float* g1 = (const float*)d_in[5];
    const float* b1 = (const float*)d_in[6];
    const float* m1 = (const float*)d_in[7];
    const float* v1 = (const float*)d_in[8];
    const float* W2 = (const float*)d_in[9];
    const float* g2 = (const float*)d_in[10];
    const float* b2 = (const float*)d_in[11];
    const float* m2 = (const float*)d_in[12];
    const float* v2 = (const float*)d_in[13];

    const int P = in_sizes[2];                       // 64000
    const int B = out_size / (COUT * YG * XG);       // 4

    float* pooled = (float*)d_ws;
    int*   winner = (int*)((char*)d_ws + (size_t)COUT * P * sizeof(float));

    // Fragment scratch lives in the tail of d_out (scatter overwrites it last).
    char* fragbase = (char*)d_out + (size_t)out_size * sizeof(float) - 11264;
    unsigned short* w1f  = (unsigned short*)fragbase;            // 2048 B
    unsigned short* w2f  = (unsigned short*)(fragbase + 2048);   // 8192 B
    float*          bb2v = (float*)(fragbase + 10240);           // 256 B

    const int nwin4 = (B * YG * XG) / 4;             // 214272
    precompute_kernel<<<(nwin4 + 255) / 256, 256, 0, stream>>>(
        W1, g1, b1, m1, v1, W2, g2, b2, m2, v2, w1f, w2f, bb2v,
        (int4*)winner, nwin4);

    pillar_mlp_kernel<<<(P + 7) / 8, 256, 0, stream>>>(
        pillars, coors, npp, w1f, w2f, bb2v, pooled, winner, P);

    const int ntx = (XG + TILE - 1) / TILE;          // 7
    scatter_kernel<<<B * YG * ntx, 256, 0, stream>>>(
        (const float4*)pooled, winner, (f32x4*)d_out, ntx);
}